// Round 15
// baseline (88.353 us; speedup 1.0000x reference)
//
#include <hip/hip_runtime.h>
#include <hip/hip_bf16.h>

// Problem constants: M=100000 points, K=27 offsets, Cin=Cout=64.
// R15: R12 base (single-segment 64B fp8 row gathers, pair-packed 1KB W frags,
// consume-immediate schedule, 128 rows/4 waves/782 blocks) + index-range
// 2-pass K-loop: pass 0 gathers only rows < 50000 (lower 3.2MB of the table),
// pass 1 only rows >= 50000; the other pass reads the zero row (coalesces to
// ~1 segment/wave). Entire grid is co-resident -> passes form global epochs,
// each epoch's gather window fits per-XCD L2 (3.2MB < 4MiB).
#define NPTS 100000
#define KOFF 27
#define KPAD 28          // padded K: tile 27 = zero weights + zero-row gathers
#define NCH  64
#define HALF_BYTES (50000 * 64)
#define ZOFF (NPTS * 64)

typedef __attribute__((ext_vector_type(4))) float f32x4;
typedef __attribute__((ext_vector_type(4))) unsigned int u32x4;
typedef __attribute__((ext_vector_type(2))) long long2_t;   // 16B, .x/.y = i64

// feats fp32 (M x 64) -> fp8 e4m3 swizzled rows. Row byte p = lk*16 + h*8 + j
// holds channel c = h*32 + lk*8 + j. One thread per (m, lk) 16B block.
// Row NPTS all-zero (gather target for invalid / other-pass entries).
__global__ void convert_feats_kernel(const float* __restrict__ feats,
                                     unsigned char* __restrict__ f8) {
  int tid = blockIdx.x * 256 + threadIdx.x;
  const int total = (NPTS + 1) * 4;
  if (tid >= total) return;
  const int m  = tid >> 2;
  const int lk = tid & 3;
  unsigned int w0 = 0, w1 = 0, w2 = 0, w3 = 0;
  if (m < NPTS) {
    const float* r = feats + (size_t)m * NCH + lk * 8;
    const float4 a = *reinterpret_cast<const float4*>(r);          // c0 j0-3
    const float4 b = *reinterpret_cast<const float4*>(r + 4);      // c0 j4-7
    const float4 c = *reinterpret_cast<const float4*>(r + 32);     // c1 j0-3
    const float4 d = *reinterpret_cast<const float4*>(r + 36);     // c1 j4-7
    int p;
    p = __builtin_amdgcn_cvt_pk_fp8_f32(a.x, a.y, 0, false);
    p = __builtin_amdgcn_cvt_pk_fp8_f32(a.z, a.w, p, true);  w0 = (unsigned)p;
    p = __builtin_amdgcn_cvt_pk_fp8_f32(b.x, b.y, 0, false);
    p = __builtin_amdgcn_cvt_pk_fp8_f32(b.z, b.w, p, true);  w1 = (unsigned)p;
    p = __builtin_amdgcn_cvt_pk_fp8_f32(c.x, c.y, 0, false);
    p = __builtin_amdgcn_cvt_pk_fp8_f32(c.z, c.w, p, true);  w2 = (unsigned)p;
    p = __builtin_amdgcn_cvt_pk_fp8_f32(d.x, d.y, 0, false);
    p = __builtin_amdgcn_cvt_pk_fp8_f32(d.z, d.w, p, true);  w3 = (unsigned)p;
  }
  *reinterpret_cast<u32x4*>(f8 + (size_t)m * 64 + lk * 16) = u32x4{w0, w1, w2, w3};
}

// weight fp32 [k][cin][cout] -> fp8 pair-packed fragments: block (ko, nt) is
// 1KB; lane L's 16B at L*16; byte h*8+j holds W[ko][h*32 + 8*(L>>4) + j][
// nt*16 + (L&15)]. One 16B load/lane yields both cin-chunk fragments.
__global__ void convert_weight_kernel(const float* __restrict__ w,
                                      unsigned char* __restrict__ wt) {
  int tid = blockIdx.x * 256 + threadIdx.x;
  if (tid >= KPAD * NCH * NCH) return;
  int ko  = tid >> 12;
  int rem = tid & 4095;
  int c   = rem >> 6;
  int o   = rem & 63;
  float val = (ko < KOFF) ? w[(size_t)ko * 4096 + c * 64 + o] : 0.0f;
  int p8 = __builtin_amdgcn_cvt_pk_fp8_f32(val, 0.0f, 0, false);
  const int h  = c >> 5;
  const int kk = c & 31;
  const int L  = ((kk >> 3) << 4) | (o & 15);
  int dst = ((ko * 4) + (o >> 4)) * 1024 + L * 16 + h * 8 + (kk & 7);
  wt[dst] = (unsigned char)(p8 & 0xff);
}

// Main kernel: block = 128 rows, 4 waves; wave owns 32 rows (2 row-tiles of
// 16) x 64 cout x 28 kos x 2 index-range passes.
__global__ __launch_bounds__(256, 4)
void spconv_kernel(const unsigned char* __restrict__ f8,       // (NPTS+1)x64 fp8 swz
                   const int* __restrict__ rulebook,           // NPTS x 27 int32
                   const unsigned char* __restrict__ wl,       // pair-packed fp8 W
                   const float* __restrict__ feats,            // NPTS x 64 fp32
                   const float* __restrict__ bias,             // 64 fp32
                   float* __restrict__ out) {                  // NPTS x 64 fp32
  __shared__ int s_off[2][128][KPAD];  // BYTE offsets per pass (other -> ZOFF)
  __shared__ int s_cnt[128];

  const int tid = threadIdx.x;
  const int m0  = blockIdx.x * 128;

  if (tid < 128) s_cnt[tid] = 0;
  __syncthreads();

  for (int f = tid; f < 128 * KPAD; f += 256) {
    int r = f / KPAD, k = f - r * KPAD;
    int m = m0 + r;
    int off = ZOFF;
    if (m < NPTS && k < KOFF) {
      int v = rulebook[(size_t)m * KOFF + k];
      if (v >= 0) { off = v * 64; atomicAdd(&s_cnt[r], 1); }
    }
    const bool lo = off < HALF_BYTES;
    s_off[0][r][k] = lo ? off : ZOFF;
    s_off[1][r][k] = lo ? ZOFF : off;
  }
  __syncthreads();

  const int wave = tid >> 6;
  const int lane = tid & 63;
  const int lr   = lane & 15;
  const int lk   = lane >> 4;
  const int lk16 = lk * 16;            // byte offset of lane's 16B within row
  const int row0 = wave * 32 + lr;
  const int row1 = wave * 32 + 16 + lr;

  const char* fbase = (const char*)f8;
  const char* wlane = (const char*)wl + lane * 16;

  f32x4 acc0[4] = {f32x4{0,0,0,0}, f32x4{0,0,0,0}, f32x4{0,0,0,0}, f32x4{0,0,0,0}};
  f32x4 acc1[4] = {f32x4{0,0,0,0}, f32x4{0,0,0,0}, f32x4{0,0,0,0}, f32x4{0,0,0,0}};

  // A: 2 ko-sets x 2 row-tiles, 16B each (.x=chunk0, .y=chunk1).
  long2_t A0r0, A0r1, A1r0, A1r1;
  // B: single set, 4 pair-packed frags (nt 0..3), reloaded after consumption.
  long2_t B0, B1, B2, B3;

#define LOADA(R0, R1, KO) {                                                   \
    R0 = *reinterpret_cast<const long2_t*>(fbase + (size_t)(unsigned)soff[row0][(KO)] + lk16); \
    R1 = *reinterpret_cast<const long2_t*>(fbase + (size_t)(unsigned)soff[row1][(KO)] + lk16); \
  }

#define LOADB(KO) {                                                           \
    const char* wb_ = wlane + (size_t)(KO) * 4096;                            \
    B0 = *reinterpret_cast<const long2_t*>(wb_ + 0 * 1024);                   \
    B1 = *reinterpret_cast<const long2_t*>(wb_ + 1 * 1024);                   \
    B2 = *reinterpret_cast<const long2_t*>(wb_ + 2 * 1024);                   \
    B3 = *reinterpret_cast<const long2_t*>(wb_ + 3 * 1024);                   \
  }

#define MFMA_STEP(R0, R1) {                                                   \
    acc0[0] = __builtin_amdgcn_mfma_f32_16x16x32_fp8_fp8(R0.x, B0.x, acc0[0],0,0,0);\
    acc0[0] = __builtin_amdgcn_mfma_f32_16x16x32_fp8_fp8(R0.y, B0.y, acc0[0],0,0,0);\
    acc1[0] = __builtin_amdgcn_mfma_f32_16x16x32_fp8_fp8(R1.x, B0.x, acc1[0],0,0,0);\
    acc1[0] = __builtin_amdgcn_mfma_f32_16x16x32_fp8_fp8(R1.y, B0.y, acc1[0],0,0,0);\
    acc0[1] = __builtin_amdgcn_mfma_f32_16x16x32_fp8_fp8(R0.x, B1.x, acc0[1],0,0,0);\
    acc0[1] = __builtin_amdgcn_mfma_f32_16x16x32_fp8_fp8(R0.y, B1.y, acc0[1],0,0,0);\
    acc1[1] = __builtin_amdgcn_mfma_f32_16x16x32_fp8_fp8(R1.x, B1.x, acc1[1],0,0,0);\
    acc1[1] = __builtin_amdgcn_mfma_f32_16x16x32_fp8_fp8(R1.y, B1.y, acc1[1],0,0,0);\
    acc0[2] = __builtin_amdgcn_mfma_f32_16x16x32_fp8_fp8(R0.x, B2.x, acc0[2],0,0,0);\
    acc0[2] = __builtin_amdgcn_mfma_f32_16x16x32_fp8_fp8(R0.y, B2.y, acc0[2],0,0,0);\
    acc1[2] = __builtin_amdgcn_mfma_f32_16x16x32_fp8_fp8(R1.x, B2.x, acc1[2],0,0,0);\
    acc1[2] = __builtin_amdgcn_mfma_f32_16x16x32_fp8_fp8(R1.y, B2.y, acc1[2],0,0,0);\
    acc0[3] = __builtin_amdgcn_mfma_f32_16x16x32_fp8_fp8(R0.x, B3.x, acc0[3],0,0,0);\
    acc0[3] = __builtin_amdgcn_mfma_f32_16x16x32_fp8_fp8(R0.y, B3.y, acc0[3],0,0,0);\
    acc1[3] = __builtin_amdgcn_mfma_f32_16x16x32_fp8_fp8(R1.x, B3.x, acc1[3],0,0,0);\
    acc1[3] = __builtin_amdgcn_mfma_f32_16x16x32_fp8_fp8(R1.y, B3.y, acc1[3],0,0,0);\
  }

  #pragma unroll 1
  for (int pass = 0; pass < 2; ++pass) {
    const int (*soff)[KPAD] = s_off[pass];

    LOADA(A0r0, A0r1, 0)
    LOADA(A1r0, A1r1, 1)
    LOADB(0)

    #pragma unroll 1
    for (int kk = 0; kk < KPAD / 2; ++kk) {
      const int ko = kk * 2;
      MFMA_STEP(A0r0, A0r1)                         // consumes A(ko), B(ko)
      LOADB(ko + 1)
      if (ko + 2 < KPAD) LOADA(A0r0, A0r1, ko + 2)
      MFMA_STEP(A1r0, A1r1)                         // consumes A(ko+1), B(ko+1)
      if (ko + 2 < KPAD) LOADB(ko + 2)
      if (ko + 3 < KPAD) LOADA(A1r0, A1r1, ko + 3)
    }
  }
#undef LOADA
#undef LOADB
#undef MFMA_STEP

  // Epilogue: /denom + bias + residual.
  #pragma unroll
  for (int rt = 0; rt < 2; ++rt) {
    #pragma unroll
    for (int nt = 0; nt < 4; ++nt) {
      const int col = nt * 16 + lr;
      const float b = bias[col];
      #pragma unroll
      for (int i = 0; i < 4; ++i) {
        const int rl = wave * 32 + rt * 16 + lk * 4 + i;
        const int m  = m0 + rl;
        if (m < NPTS) {
          const float denom = (float)max(s_cnt[rl], 1);
          const float a = (rt == 0) ? acc0[nt][i] : acc1[nt][i];
          out[(size_t)m * NCH + col] =
              a / denom + b + feats[(size_t)m * NCH + col];
        }
      }
    }
  }
}

extern "C" void kernel_launch(void* const* d_in, const int* in_sizes, int n_in,
                              void* d_out, int out_size, void* d_ws, size_t ws_size,
                              hipStream_t stream) {
  const float* feats    = (const float*)d_in[0];
  const int*   rulebook = (const int*)d_in[1];
  const float* weight   = (const float*)d_in[2];
  const float* bias     = (const float*)d_in[3];
  float* out = (float*)d_out;

  // Workspace: [0, ~6.4MB) feats fp8 swizzled rows; then weights fp8 (112KB).
  unsigned char* f8 = (unsigned char*)d_ws;
  const size_t f8_bytes = (size_t)(NPTS + 1) * NCH;          // 6,400,064
  const size_t wt_off   = (f8_bytes + 1023) & ~(size_t)1023;
  unsigned char* wl = (unsigned char*)((char*)d_ws + wt_off);

  {
    const int total = (NPTS + 1) * 4;                        // 16B blocks
    convert_feats_kernel<<<(total + 255) / 256, 256, 0, stream>>>(feats, f8);
  }
  {
    const int n = KPAD * NCH * NCH;
    convert_weight_kernel<<<(n + 255) / 256, 256, 0, stream>>>(weight, wl);
  }
  {
    const int nblk = (NPTS + 127) / 128;   // 782
    spconv_kernel<<<nblk, 256, 0, stream>>>(f8, rulebook, wl, feats, bias, out);
  }
}

// Round 16
// 76.287 us; speedup vs baseline: 1.1582x; 1.1582x over previous
//
#include <hip/hip_runtime.h>
#include <hip/hip_bf16.h>

// Problem constants: M=100000 points, K=27 offsets, Cin=Cout=64.
// R16: R12 base (fp8, single-segment 64B row gathers, pair-packed 1KB W
// frags, 128 rows / 4 waves / 782 blocks) with a REAL deep pipeline:
// group = 2 kos per iteration; A triple-buffered (issued 2 iterations before
// use, ~800+ cyc cover for HBM-miss gathers); B double-buffered (reloaded
// post-consume). sched_barrier(0) pins load issue above the MFMA block
// (R10's depth-4 silently collapsed: compiler sank the loads, VGPR=60).
#define NPTS 100000
#define KOFF 27
#define KPAD 28          // padded K: tile 27 = zero weights + zero-row gathers
#define NCH  64

typedef __attribute__((ext_vector_type(4))) float f32x4;
typedef __attribute__((ext_vector_type(4))) unsigned int u32x4;
typedef __attribute__((ext_vector_type(2))) long long2_t;   // 16B, .x/.y = i64

// feats fp32 (M x 64) -> fp8 e4m3 swizzled rows. Row byte p = lk*16 + h*8 + j
// holds channel c = h*32 + lk*8 + j. One thread per (m, lk) 16B block.
// Row NPTS all-zero (gather target for invalid rulebook entries).
__global__ void convert_feats_kernel(const float* __restrict__ feats,
                                     unsigned char* __restrict__ f8) {
  int tid = blockIdx.x * 256 + threadIdx.x;
  const int total = (NPTS + 1) * 4;
  if (tid >= total) return;
  const int m  = tid >> 2;
  const int lk = tid & 3;
  unsigned int w0 = 0, w1 = 0, w2 = 0, w3 = 0;
  if (m < NPTS) {
    const float* r = feats + (size_t)m * NCH + lk * 8;
    const float4 a = *reinterpret_cast<const float4*>(r);          // c0 j0-3
    const float4 b = *reinterpret_cast<const float4*>(r + 4);      // c0 j4-7
    const float4 c = *reinterpret_cast<const float4*>(r + 32);     // c1 j0-3
    const float4 d = *reinterpret_cast<const float4*>(r + 36);     // c1 j4-7
    int p;
    p = __builtin_amdgcn_cvt_pk_fp8_f32(a.x, a.y, 0, false);
    p = __builtin_amdgcn_cvt_pk_fp8_f32(a.z, a.w, p, true);  w0 = (unsigned)p;
    p = __builtin_amdgcn_cvt_pk_fp8_f32(b.x, b.y, 0, false);
    p = __builtin_amdgcn_cvt_pk_fp8_f32(b.z, b.w, p, true);  w1 = (unsigned)p;
    p = __builtin_amdgcn_cvt_pk_fp8_f32(c.x, c.y, 0, false);
    p = __builtin_amdgcn_cvt_pk_fp8_f32(c.z, c.w, p, true);  w2 = (unsigned)p;
    p = __builtin_amdgcn_cvt_pk_fp8_f32(d.x, d.y, 0, false);
    p = __builtin_amdgcn_cvt_pk_fp8_f32(d.z, d.w, p, true);  w3 = (unsigned)p;
  }
  *reinterpret_cast<u32x4*>(f8 + (size_t)m * 64 + lk * 16) = u32x4{w0, w1, w2, w3};
}

// weight fp32 [k][cin][cout] -> fp8 pair-packed fragments: block (ko, nt) is
// 1KB; lane L's 16B at L*16; byte h*8+j holds W[ko][h*32 + 8*(L>>4) + j][
// nt*16 + (L&15)]. One 16B load/lane yields both cin-chunk fragments.
__global__ void convert_weight_kernel(const float* __restrict__ w,
                                      unsigned char* __restrict__ wt) {
  int tid = blockIdx.x * 256 + threadIdx.x;
  if (tid >= KPAD * NCH * NCH) return;
  int ko  = tid >> 12;
  int rem = tid & 4095;
  int c   = rem >> 6;
  int o   = rem & 63;
  float val = (ko < KOFF) ? w[(size_t)ko * 4096 + c * 64 + o] : 0.0f;
  int p8 = __builtin_amdgcn_cvt_pk_fp8_f32(val, 0.0f, 0, false);
  const int h  = c >> 5;
  const int kk = c & 31;
  const int L  = ((kk >> 3) << 4) | (o & 15);
  int dst = ((ko * 4) + (o >> 4)) * 1024 + L * 16 + h * 8 + (kk & 7);
  wt[dst] = (unsigned char)(p8 & 0xff);
}

struct AGrp { long2_t k0r0, k0r1, k1r0, k1r1; };           // 2 kos x 2 row-tiles
struct BGrp { long2_t a0, a1, a2, a3, b0, b1, b2, b3; };   // 2 kos x 4 nt frags

// Main kernel: block = 128 rows, 4 waves; wave owns 32 rows (2 row-tiles of
// 16) x 64 cout x 28 kos (14 groups of 2).
__global__ __launch_bounds__(256, 2)
void spconv_kernel(const unsigned char* __restrict__ f8,       // (NPTS+1)x64 fp8 swz
                   const int* __restrict__ rulebook,           // NPTS x 27 int32
                   const unsigned char* __restrict__ wl,       // pair-packed fp8 W
                   const float* __restrict__ feats,            // NPTS x 64 fp32
                   const float* __restrict__ bias,             // 64 fp32
                   float* __restrict__ out) {                  // NPTS x 64 fp32
  __shared__ int s_off[128][KPAD];   // BYTE offsets into f8 (idx*64)
  __shared__ int s_cnt[128];

  const int tid = threadIdx.x;
  const int m0  = blockIdx.x * 128;

  if (tid < 128) s_cnt[tid] = 0;
  __syncthreads();

  for (int f = tid; f < 128 * KPAD; f += 256) {
    int r = f / KPAD, k = f - r * KPAD;
    int m = m0 + r;
    int off = NPTS * 64;
    if (m < NPTS && k < KOFF) {
      int v = rulebook[(size_t)m * KOFF + k];
      if (v >= 0) { off = v * 64; atomicAdd(&s_cnt[r], 1); }
    }
    s_off[r][k] = off;
  }
  __syncthreads();

  const int wave = tid >> 6;
  const int lane = tid & 63;
  const int lr   = lane & 15;
  const int lk   = lane >> 4;
  const int lk16 = lk * 16;            // byte offset of lane's 16B within row
  const int row0 = wave * 32 + lr;
  const int row1 = wave * 32 + 16 + lr;

  const char* fbase = (const char*)f8;
  const char* wlane = (const char*)wl + lane * 16;
  const int* soff0 = &s_off[row0][0];
  const int* soff1 = &s_off[row1][0];

  f32x4 acc0[4] = {f32x4{0,0,0,0}, f32x4{0,0,0,0}, f32x4{0,0,0,0}, f32x4{0,0,0,0}};
  f32x4 acc1[4] = {f32x4{0,0,0,0}, f32x4{0,0,0,0}, f32x4{0,0,0,0}, f32x4{0,0,0,0}};

  AGrp A0, A1, A2;     // triple-buffered A groups
  BGrp B0, B1;         // double-buffered B groups

#define LOADA(AG, G) {                                                        \
    AG.k0r0 = *reinterpret_cast<const long2_t*>(fbase + (size_t)(unsigned)soff0[2*(G)]     + lk16); \
    AG.k0r1 = *reinterpret_cast<const long2_t*>(fbase + (size_t)(unsigned)soff1[2*(G)]     + lk16); \
    AG.k1r0 = *reinterpret_cast<const long2_t*>(fbase + (size_t)(unsigned)soff0[2*(G) + 1] + lk16); \
    AG.k1r1 = *reinterpret_cast<const long2_t*>(fbase + (size_t)(unsigned)soff1[2*(G) + 1] + lk16); \
  }

#define LOADB(BG, G) {                                                        \
    const char* wb_ = wlane + (size_t)(2*(G)) * 4096;                         \
    BG.a0 = *reinterpret_cast<const long2_t*>(wb_ + 0 * 1024);                \
    BG.a1 = *reinterpret_cast<const long2_t*>(wb_ + 1 * 1024);                \
    BG.a2 = *reinterpret_cast<const long2_t*>(wb_ + 2 * 1024);                \
    BG.a3 = *reinterpret_cast<const long2_t*>(wb_ + 3 * 1024);                \
    BG.b0 = *reinterpret_cast<const long2_t*>(wb_ + 4096 + 0 * 1024);         \
    BG.b1 = *reinterpret_cast<const long2_t*>(wb_ + 4096 + 1 * 1024);         \
    BG.b2 = *reinterpret_cast<const long2_t*>(wb_ + 4096 + 2 * 1024);         \
    BG.b3 = *reinterpret_cast<const long2_t*>(wb_ + 4096 + 3 * 1024);         \
  }

#define MFMA_KO(R0, R1, F0, F1, F2, F3) {                                     \
    acc0[0] = __builtin_amdgcn_mfma_f32_16x16x32_fp8_fp8(R0.x, F0.x, acc0[0],0,0,0);\
    acc0[0] = __builtin_amdgcn_mfma_f32_16x16x32_fp8_fp8(R0.y, F0.y, acc0[0],0,0,0);\
    acc1[0] = __builtin_amdgcn_mfma_f32_16x16x32_fp8_fp8(R1.x, F0.x, acc1[0],0,0,0);\
    acc1[0] = __builtin_amdgcn_mfma_f32_16x16x32_fp8_fp8(R1.y, F0.y, acc1[0],0,0,0);\
    acc0[1] = __builtin_amdgcn_mfma_f32_16x16x32_fp8_fp8(R0.x, F1.x, acc0[1],0,0,0);\
    acc0[1] = __builtin_amdgcn_mfma_f32_16x16x32_fp8_fp8(R0.y, F1.y, acc0[1],0,0,0);\
    acc1[1] = __builtin_amdgcn_mfma_f32_16x16x32_fp8_fp8(R1.x, F1.x, acc1[1],0,0,0);\
    acc1[1] = __builtin_amdgcn_mfma_f32_16x16x32_fp8_fp8(R1.y, F1.y, acc1[1],0,0,0);\
    acc0[2] = __builtin_amdgcn_mfma_f32_16x16x32_fp8_fp8(R0.x, F2.x, acc0[2],0,0,0);\
    acc0[2] = __builtin_amdgcn_mfma_f32_16x16x32_fp8_fp8(R0.y, F2.y, acc0[2],0,0,0);\
    acc1[2] = __builtin_amdgcn_mfma_f32_16x16x32_fp8_fp8(R1.x, F2.x, acc1[2],0,0,0);\
    acc1[2] = __builtin_amdgcn_mfma_f32_16x16x32_fp8_fp8(R1.y, F2.y, acc1[2],0,0,0);\
    acc0[3] = __builtin_amdgcn_mfma_f32_16x16x32_fp8_fp8(R0.x, F3.x, acc0[3],0,0,0);\
    acc0[3] = __builtin_amdgcn_mfma_f32_16x16x32_fp8_fp8(R0.y, F3.y, acc0[3],0,0,0);\
    acc1[3] = __builtin_amdgcn_mfma_f32_16x16x32_fp8_fp8(R1.x, F3.x, acc1[3],0,0,0);\
    acc1[3] = __builtin_amdgcn_mfma_f32_16x16x32_fp8_fp8(R1.y, F3.y, acc1[3],0,0,0);\
  }

// iteration G: prefetch A(G+2) into ANXT (pinned above MFMAs), compute group G
// from AUSE/BUSE, then reload BUSE with group G+2 (freed this iteration).
#define ITER(G, AUSE, ANXT, BUSE) {                                           \
    LOADA(ANXT, (G) + 2)                                                      \
    __builtin_amdgcn_sched_barrier(0);                                        \
    MFMA_KO(AUSE.k0r0, AUSE.k0r1, BUSE.a0, BUSE.a1, BUSE.a2, BUSE.a3)         \
    MFMA_KO(AUSE.k1r0, AUSE.k1r1, BUSE.b0, BUSE.b1, BUSE.b2, BUSE.b3)         \
    LOADB(BUSE, (G) + 2)                                                      \
  }

#define ITER_TAIL(AUSE, BUSE) {                                               \
    MFMA_KO(AUSE.k0r0, AUSE.k0r1, BUSE.a0, BUSE.a1, BUSE.a2, BUSE.a3)         \
    MFMA_KO(AUSE.k1r0, AUSE.k1r1, BUSE.b0, BUSE.b1, BUSE.b2, BUSE.b3)         \
  }

  // Prologue: groups 0,1 of A and B in flight.
  LOADA(A0, 0)
  LOADA(A1, 1)
  LOADB(B0, 0)
  LOADB(B1, 1)

  // 14 groups total: 2 x 6-iteration pattern (g=0..11) + tail g=12,13.
  #pragma unroll 1
  for (int half = 0; half < 2; ++half) {
    const int g = half * 6;
    ITER(g + 0, A0, A2, B0)
    ITER(g + 1, A1, A0, B1)
    ITER(g + 2, A2, A1, B0)
    ITER(g + 3, A0, A2, B1)
    ITER(g + 4, A1, A0, B0)
    ITER(g + 5, A2, A1, B1)
  }
  ITER_TAIL(A0, B0)   // g=12 (A0 loaded at g=10, B0 at g=10)
  ITER_TAIL(A1, B1)   // g=13 (A1 loaded at g=11, B1 at g=11)

#undef LOADA
#undef LOADB
#undef MFMA_KO
#undef ITER
#undef ITER_TAIL

  // Epilogue: /denom + bias + residual.
  #pragma unroll
  for (int rt = 0; rt < 2; ++rt) {
    #pragma unroll
    for (int nt = 0; nt < 4; ++nt) {
      const int col = nt * 16 + lr;
      const float b = bias[col];
      #pragma unroll
      for (int i = 0; i < 4; ++i) {
        const int rl = wave * 32 + rt * 16 + lk * 4 + i;
        const int m  = m0 + rl;
        if (m < NPTS) {
          const float denom = (float)max(s_cnt[rl], 1);
          const float a = (rt == 0) ? acc0[nt][i] : acc1[nt][i];
          out[(size_t)m * NCH + col] =
              a / denom + b + feats[(size_t)m * NCH + col];
        }
      }
    }
  }
}

extern "C" void kernel_launch(void* const* d_in, const int* in_sizes, int n_in,
                              void* d_out, int out_size, void* d_ws, size_t ws_size,
                              hipStream_t stream) {
  const float* feats    = (const float*)d_in[0];
  const int*   rulebook = (const int*)d_in[1];
  const float* weight   = (const float*)d_in[2];
  const float* bias     = (const float*)d_in[3];
  float* out = (float*)d_out;

  // Workspace: [0, ~6.4MB) feats fp8 swizzled rows; then weights fp8 (112KB).
  unsigned char* f8 = (unsigned char*)d_ws;
  const size_t f8_bytes = (size_t)(NPTS + 1) * NCH;          // 6,400,064
  const size_t wt_off   = (f8_bytes + 1023) & ~(size_t)1023;
  unsigned char* wl = (unsigned char*)((char*)d_ws + wt_off);

  {
    const int total = (NPTS + 1) * 4;                        // 16B blocks
    convert_feats_kernel<<<(total + 255) / 256, 256, 0, stream>>>(feats, f8);
  }
  {
    const int n = KPAD * NCH * NCH;
    convert_weight_kernel<<<(n + 255) / 256, 256, 0, stream>>>(weight, wl);
  }
  {
    const int nblk = (NPTS + 127) / 128;   // 782
    spconv_kernel<<<nblk, 256, 0, stream>>>(f8, rulebook, wl, feats, bias, out);
  }
}